// Round 1
// baseline (285.649 us; speedup 1.0000x reference)
//
#include <hip/hip_runtime.h>
#include <stdint.h>

// Problem constants (B=2, H=8, N=2048, D=64, f32 in/out).
#define B_ 2
#define H_ 8
#define N_ 2048
#define D_ 64
#define BH_ (B_ * H_)
#define NROWS (BH_ * N_)   // 32768
#define TI 128             // rows per workgroup (== block size), thread-per-row
#define TJ 256             // j-segment width
#define NSEG (N_ / TJ)     // 8
#define ITILES (N_ / TI)   // 16
#define EPSF 8e-3f         // margin below which we re-resolve the row in f64

using u64 = unsigned long long;
using u32 = unsigned int;

// ---------------------------------------------------------------------------
// Phase 1: per (row, j-segment) argmin of d2 = max(|q|^2+|k|^2-2 q.k, 0).
// Thread t owns row i = it*TI + t. All threads sweep the same j (uniform) so
// k-row loads are wave-wide broadcasts (L1/L2 served). Track best AND second
// best d2 in the segment; pack (f32 bits << 32) | j so u64-min == (min d2,
// first index on ties) — matches np.argmax's first-occurrence rule.
// ---------------------------------------------------------------------------
__global__ __launch_bounds__(TI) void phase1_argmin(
    const float* __restrict__ q, const float* __restrict__ k,
    u64* __restrict__ bestseg, u64* __restrict__ secseg)
{
  const int bh = blockIdx.y;
  const int it = blockIdx.x / NSEG;
  const int jt = blockIdx.x - it * NSEG;
  const int i0 = it * TI, j0 = jt * TJ;
  const int imax = i0 + TI - 1;
  if (j0 > imax) return;  // segment entirely above the causal diagonal

  __shared__ float ksq_s[TJ];
  const int tid = threadIdx.x;
  const float* kb = k + (size_t)bh * N_ * D_;

  // |k_j|^2 for this segment -> LDS (each thread does 2 rows)
  #pragma unroll
  for (int e = 0; e < TJ / TI; ++e) {
    const int jl = tid + e * TI;
    const float4* kr = (const float4*)(kb + (size_t)(j0 + jl) * D_);
    float s0 = 0.f, s1 = 0.f, s2 = 0.f, s3 = 0.f;
    #pragma unroll
    for (int t = 0; t < D_ / 4; ++t) {
      float4 kv = kr[t];
      s0 = fmaf(kv.x, kv.x, s0); s1 = fmaf(kv.y, kv.y, s1);
      s2 = fmaf(kv.z, kv.z, s2); s3 = fmaf(kv.w, kv.w, s3);
    }
    ksq_s[jl] = (s0 + s1) + (s2 + s3);
  }

  // q row into registers (64 VGPRs) + |q|^2
  const int i = i0 + tid;
  const float4* qr = (const float4*)(q + ((size_t)bh * N_ + i) * D_);
  float4 qv[D_ / 4];
  float qs0 = 0.f, qs1 = 0.f, qs2 = 0.f, qs3 = 0.f;
  #pragma unroll
  for (int t = 0; t < D_ / 4; ++t) {
    qv[t] = qr[t];
    qs0 = fmaf(qv[t].x, qv[t].x, qs0); qs1 = fmaf(qv[t].y, qv[t].y, qs1);
    qs2 = fmaf(qv[t].z, qv[t].z, qs2); qs3 = fmaf(qv[t].w, qv[t].w, qs3);
  }
  const float qsq = (qs0 + qs1) + (qs2 + qs3);
  __syncthreads();

  const int jcnt = min(TJ, imax - j0 + 1);  // uniform loop bound
  float best = __int_as_float(0x7f800000);  // +inf
  float second = best;
  int bj = j0;
  for (int jj = 0; jj < jcnt; ++jj) {
    const float4* kr = (const float4*)(kb + (size_t)(j0 + jj) * D_);
    float a0 = 0.f, a1 = 0.f, a2 = 0.f, a3 = 0.f;
    #pragma unroll
    for (int t = 0; t < D_ / 4; ++t) {
      float4 kv = kr[t];  // uniform address -> broadcast
      a0 = fmaf(qv[t].x, kv.x, a0); a1 = fmaf(qv[t].y, kv.y, a1);
      a2 = fmaf(qv[t].z, kv.z, a2); a3 = fmaf(qv[t].w, kv.w, a3);
    }
    const float dot = (a0 + a1) + (a2 + a3);
    const float raw = (qsq + ksq_s[jj]) - 2.0f * dot;
    const float d2 = fmaxf(raw, 0.0f);
    const int j = j0 + jj;
    if (j <= i) {                 // causal
      if (d2 < best) { second = best; best = d2; bj = j; }
      else if (d2 < second) { second = d2; }
    }
  }
  const size_t r = (size_t)bh * N_ + i;
  bestseg[r * NSEG + jt] = ((u64)__float_as_uint(best) << 32) | (u32)bj;
  secseg[r * NSEG + jt]  = ((u64)__float_as_uint(second) << 32);
}

// ---------------------------------------------------------------------------
// Combine per-segment results: global best (u64-min keeps first index on
// ties) + true global second-best value; flag rows whose margin < EPSF.
// ---------------------------------------------------------------------------
__global__ __launch_bounds__(256) void combine_segs(
    const u64* __restrict__ bestseg, const u64* __restrict__ secseg,
    u32* __restrict__ idx_flag)
{
  const int r = blockIdx.x * 256 + threadIdx.x;
  if (r >= NROWS) return;
  u64 b0 = ~0ull, b1 = ~0ull;
  int sstar = 0;
  #pragma unroll
  for (int s = 0; s < NSEG; ++s) {
    const u64 kk = bestseg[(size_t)r * NSEG + s];
    if (kk < b0) { b1 = b0; b0 = kk; sstar = s; }
    else if (kk < b1) { b1 = kk; }
  }
  u32 sec_bits = (u32)(b1 >> 32);
  const u32 sk = (u32)(secseg[(size_t)r * NSEG + sstar] >> 32);
  sec_bits = min(sec_bits, sk);
  const float best = __uint_as_float((u32)(b0 >> 32));
  const float secf = __uint_as_float(sec_bits);  // may be +inf / NaN pattern
  const bool flag = (secf - best) < EPSF;        // NaN -> false (unflagged)
  idx_flag[r] = (u32)(b0 & 0xFFFFu) | (flag ? 0x80000000u : 0u);
}

// ---------------------------------------------------------------------------
// Exact f64 re-resolution of flagged (near-tie) rows. ~tens of rows expected.
// ---------------------------------------------------------------------------
__global__ __launch_bounds__(256) void exact_fix(
    const float* __restrict__ q, const float* __restrict__ k,
    u32* __restrict__ idx_flag)
{
  __shared__ double qd[D_];
  __shared__ double sd[256];
  __shared__ int sj[256];
  const int tid = threadIdx.x;
  const int rbase = blockIdx.x * (NROWS / 512);  // 64 rows per block
  for (int rr = 0; rr < NROWS / 512; ++rr) {
    const int r = rbase + rr;
    const u32 f = idx_flag[r];              // uniform within the block
    if (!(f & 0x80000000u)) continue;
    const int bh = r >> 11;                 // N_ = 2048
    const int i = r & (N_ - 1);
    const float* qr = q + (size_t)r * D_;
    const float* kb = k + (size_t)bh * N_ * D_;
    if (tid < D_) qd[tid] = (double)qr[tid];
    __syncthreads();
    double qsqd = 0.0;
    for (int d = 0; d < D_; ++d) qsqd = fma(qd[d], qd[d], qsqd);
    double bbest = 1e300;
    int bjj = 0;
    for (int j = tid; j <= i; j += 256) {
      const float* kr = kb + (size_t)j * D_;
      double a0 = 0, a1 = 0, s0 = 0, s1 = 0;
      for (int d = 0; d < D_; d += 2) {
        const double k0 = (double)kr[d], k1 = (double)kr[d + 1];
        a0 = fma(qd[d], k0, a0);     a1 = fma(qd[d + 1], k1, a1);
        s0 = fma(k0, k0, s0);        s1 = fma(k1, k1, s1);
      }
      const double dot = a0 + a1, ksq = s0 + s1;
      const double raw = (qsqd + ksq) - 2.0 * dot;
      const double d2 = raw > 0.0 ? raw : 0.0;
      if (d2 < bbest) { bbest = d2; bjj = j; }  // ascending j -> first on tie
    }
    sd[tid] = bbest; sj[tid] = bjj;
    __syncthreads();
    for (int s = 128; s > 0; s >>= 1) {
      if (tid < s) {
        const double ob = sd[tid + s]; const int oj = sj[tid + s];
        if (ob < sd[tid] || (ob == sd[tid] && oj < sj[tid])) {
          sd[tid] = ob; sj[tid] = oj;
        }
      }
      __syncthreads();
    }
    if (tid == 0) idx_flag[r] = (u32)sj[0];  // clears flag bit
    __syncthreads();
  }
}

// ---------------------------------------------------------------------------
// Gather: out[r, :] = v[bh, idx[r], :]  (float4-vectorized)
// ---------------------------------------------------------------------------
__global__ __launch_bounds__(256) void gather_v(
    const float* __restrict__ v, const u32* __restrict__ idx_flag,
    float* __restrict__ out)
{
  const int g = blockIdx.x * 256 + threadIdx.x;  // NROWS*16 total
  const int r = g >> 4, c = g & 15;
  const u32 idx = idx_flag[r] & 0xFFFFu;
  const int bh = r >> 11;
  const float4 val =
      ((const float4*)(v + ((size_t)bh * N_ + idx) * D_))[c];
  ((float4*)(out + (size_t)r * D_))[c] = val;
}

// ---------------------------------------------------------------------------
extern "C" void kernel_launch(void* const* d_in, const int* in_sizes, int n_in,
                              void* d_out, int out_size, void* d_ws,
                              size_t ws_size, hipStream_t stream) {
  const float* q = (const float*)d_in[0];
  const float* k = (const float*)d_in[1];
  const float* v = (const float*)d_in[2];
  float* out = (float*)d_out;

  // Segment scratch lives in d_out (8 MB; fully overwritten by gather_v).
  // Only idx_flag (128 KB) uses d_ws.
  u64* bestseg = (u64*)d_out;
  u64* secseg = bestseg + (size_t)NROWS * NSEG;
  u32* idx_flag = (u32*)d_ws;

  const size_t seg_bytes = (size_t)NROWS * NSEG * sizeof(u64) * 2;  // 4 MB
  hipMemsetAsync(d_out, 0xFF, seg_bytes, stream);

  dim3 g1(ITILES * NSEG, BH_);
  phase1_argmin<<<g1, TI, 0, stream>>>(q, k, bestseg, secseg);
  combine_segs<<<NROWS / 256, 256, 0, stream>>>(bestseg, secseg, idx_flag);
  exact_fix<<<512, 256, 0, stream>>>(q, k, idx_flag);
  gather_v<<<(NROWS * (D_ / 4)) / 256, 256, 0, stream>>>(v, idx_flag, out);
}

// Round 2
// 123.673 us; speedup vs baseline: 2.3097x; 2.3097x over previous
//
#include <hip/hip_runtime.h>
#include <stdint.h>

// Problem constants (B=2, H=8, N=2048, D=64, f32 in/out).
#define B_ 2
#define H_ 8
#define N_ 2048
#define D_ 64
#define BH_ (B_ * H_)
#define NROWS (BH_ * N_)      // 32768
#define TI 256                // rows per block (one thread per row)
#define TJ 128                // j-segment width
#define NSEG (N_ / TJ)        // 16
#define ITILES (N_ / TI)      // 8
#define NACT (ITILES * (ITILES + 1))  // 72 active (it,jt) tiles: sum(2it+2)
#define EPSF 8e-3f            // margin below which we re-resolve the row in f64

using u64 = unsigned long long;
using u32 = unsigned int;

// ---------------------------------------------------------------------------
// Phase 1: per (row, j-segment) argmin of d2 = max(|q|^2+|k|^2-2 q.k, 0).
// Thread t owns row i. All threads sweep the same j (uniform address -> the
// compiler scalarizes the k-row loads to s_load; q row stays in VGPRs thanks
// to __launch_bounds__(TI,2)). best packed as (f32bits<<32)|j so u64-min ==
// (min d2, first index on ties) — matches np.argmax first-occurrence.
// Grid.x enumerates only causal-active (it,jt) pairs (triangular decode).
// Layout: bestseg[jt][r], secseg[jt][r]  (coalesced write AND read).
// ---------------------------------------------------------------------------
__global__ __launch_bounds__(TI, 2) void phase1_argmin(
    const float* __restrict__ q, const float* __restrict__ k,
    u64* __restrict__ bestseg, u32* __restrict__ secseg)
{
  const int bh = blockIdx.y;
  const int x = (int)blockIdx.x;
  int it = 0;                           // offsets[it] = it*(it+1), 2it+2 segs each
  while ((it + 1) * (it + 2) <= x) ++it;
  const int jt = x - it * (it + 1);
  const int i0 = it * TI, j0 = jt * TJ;

  __shared__ float ksq_s[TJ];
  const int tid = threadIdx.x;
  const float* kb = k + (size_t)bh * N_ * D_;

  // |k_j|^2 for this segment -> LDS
  if (tid < TJ) {
    const float4* kr = (const float4*)(kb + (size_t)(j0 + tid) * D_);
    float s0 = 0.f, s1 = 0.f, s2 = 0.f, s3 = 0.f;
    #pragma unroll
    for (int t = 0; t < D_ / 4; ++t) {
      float4 kv = kr[t];
      s0 = fmaf(kv.x, kv.x, s0); s1 = fmaf(kv.y, kv.y, s1);
      s2 = fmaf(kv.z, kv.z, s2); s3 = fmaf(kv.w, kv.w, s3);
    }
    ksq_s[tid] = (s0 + s1) + (s2 + s3);
  }

  // q row into registers (64 VGPRs) + |q|^2
  const int i = i0 + tid;
  const float4* qr = (const float4*)(q + ((size_t)bh * N_ + i) * D_);
  float4 qv[D_ / 4];
  float qs0 = 0.f, qs1 = 0.f, qs2 = 0.f, qs3 = 0.f;
  #pragma unroll
  for (int t = 0; t < D_ / 4; ++t) {
    qv[t] = qr[t];
    qs0 = fmaf(qv[t].x, qv[t].x, qs0); qs1 = fmaf(qv[t].y, qv[t].y, qs1);
    qs2 = fmaf(qv[t].z, qv[t].z, qs2); qs3 = fmaf(qv[t].w, qv[t].w, qs3);
  }
  const float qsq = (qs0 + qs1) + (qs2 + qs3);
  __syncthreads();

  const int jcnt = min(TJ, (i0 + TI - 1) - j0 + 1);  // uniform (==TJ here)
  u64 b0 = ~0ull;                  // packed (best_bits, j)
  u32 s1v = 0x7F800000u;           // second-best value bits (+inf)
  for (int jj = 0; jj < jcnt; ++jj) {
    const float4* kr = (const float4*)(kb + (size_t)(j0 + jj) * D_);
    float a0 = 0.f, a1 = 0.f, a2 = 0.f, a3 = 0.f;
    #pragma unroll
    for (int t = 0; t < D_ / 4; ++t) {
      float4 kv = kr[t];  // uniform address -> scalar load
      a0 = fmaf(qv[t].x, kv.x, a0); a1 = fmaf(qv[t].y, kv.y, a1);
      a2 = fmaf(qv[t].z, kv.z, a2); a3 = fmaf(qv[t].w, kv.w, a3);
    }
    const float dot = (a0 + a1) + (a2 + a3);
    const float d2 = fmaxf((qsq + ksq_s[jj]) - 2.0f * dot, 0.0f);
    const int j = j0 + jj;
    if (j <= i) {                  // causal
      const u64 cand = ((u64)__float_as_uint(d2) << 32) | (u32)j;
      if (cand < b0) { s1v = min(s1v, (u32)(b0 >> 32)); b0 = cand; }
      else           { s1v = min(s1v, __float_as_uint(d2)); }
    }
  }
  const size_t r = (size_t)bh * N_ + i;
  bestseg[(size_t)jt * NROWS + r] = b0;
  secseg[(size_t)jt * NROWS + r] = s1v;
}

// ---------------------------------------------------------------------------
// Combine per-segment results. Only segments s <= i>>7 were written for row i
// (and all of those WERE written), so no sentinel memset is needed.
// flag rows whose best/second margin < EPSF; either set a flag bit (legacy)
// or append to a compacted list (use_list).
// ---------------------------------------------------------------------------
__global__ __launch_bounds__(256) void combine_segs(
    const u64* __restrict__ bestseg, const u32* __restrict__ secseg,
    u32* __restrict__ idx, u32* __restrict__ flaglist, u32* __restrict__ count,
    int use_list)
{
  const int r = blockIdx.x * 256 + threadIdx.x;
  if (r >= NROWS) return;
  const int i = r & (N_ - 1);
  const int smax = i >> 7;              // i / TJ
  u64 b0 = ~0ull;
  u32 s1 = 0xFFFFFFFFu;
  int sstar = 0;
  for (int s = 0; s <= smax; ++s) {
    const u64 kk = bestseg[(size_t)s * NROWS + r];
    if (kk < b0) { s1 = min(s1, (u32)(b0 >> 32)); b0 = kk; sstar = s; }
    else         { s1 = min(s1, (u32)(kk >> 32)); }
  }
  s1 = min(s1, secseg[(size_t)sstar * NROWS + r]);
  const float best = __uint_as_float((u32)(b0 >> 32));
  const float secf = __uint_as_float(s1);        // may be +inf
  const bool flag = (secf - best) < EPSF;        // NaN -> false
  if (use_list) {
    idx[r] = (u32)(b0 & 0xFFFFu);
    if (flag) { const u32 p = atomicAdd(count, 1u); flaglist[p] = r; }
  } else {
    idx[r] = (u32)(b0 & 0xFFFFu) | (flag ? 0x80000000u : 0u);
  }
}

// ---------------------------------------------------------------------------
// Exact f64 re-resolution of near-tie rows — compacted-list variant.
// ---------------------------------------------------------------------------
__global__ __launch_bounds__(256) void exact_fix_list(
    const float* __restrict__ q, const float* __restrict__ k,
    u32* __restrict__ idx, const u32* __restrict__ flaglist,
    const u32* __restrict__ count)
{
  __shared__ double qd[D_];
  __shared__ double sd[256];
  __shared__ int sj[256];
  const int tid = threadIdx.x;
  const int cnt = (int)count[0];
  for (int li = blockIdx.x; li < cnt; li += (int)gridDim.x) {
    const int r = (int)flaglist[li];
    const int bh = r >> 11;
    const int i = r & (N_ - 1);
    const float* qr = q + (size_t)r * D_;
    const float* kb = k + (size_t)bh * N_ * D_;
    if (tid < D_) qd[tid] = (double)qr[tid];
    __syncthreads();
    double qsqd = 0.0;
    for (int d = 0; d < D_; ++d) qsqd = fma(qd[d], qd[d], qsqd);
    double bbest = 1e300;
    int bjj = 0;
    for (int j = tid; j <= i; j += 256) {
      const float* kr = kb + (size_t)j * D_;
      double a0 = 0, a1 = 0, s0 = 0, s1 = 0;
      for (int d = 0; d < D_; d += 2) {
        const double k0 = (double)kr[d], k1 = (double)kr[d + 1];
        a0 = fma(qd[d], k0, a0);  a1 = fma(qd[d + 1], k1, a1);
        s0 = fma(k0, k0, s0);     s1 = fma(k1, k1, s1);
      }
      const double raw = (qsqd + (s0 + s1)) - 2.0 * (a0 + a1);
      const double d2 = raw > 0.0 ? raw : 0.0;
      if (d2 < bbest) { bbest = d2; bjj = j; }   // ascending j -> first on tie
    }
    sd[tid] = bbest; sj[tid] = bjj;
    __syncthreads();
    for (int s = 128; s > 0; s >>= 1) {
      if (tid < s) {
        const double ob = sd[tid + s]; const int oj = sj[tid + s];
        if (ob < sd[tid] || (ob == sd[tid] && oj < sj[tid])) {
          sd[tid] = ob; sj[tid] = oj;
        }
      }
      __syncthreads();
    }
    if (tid == 0) idx[r] = (u32)sj[0];
    __syncthreads();
  }
}

// Legacy scan variant (used only if ws is too small for the list).
__global__ __launch_bounds__(256) void exact_fix_scan(
    const float* __restrict__ q, const float* __restrict__ k,
    u32* __restrict__ idx)
{
  __shared__ double qd[D_];
  __shared__ double sd[256];
  __shared__ int sj[256];
  const int tid = threadIdx.x;
  const int rbase = blockIdx.x * (NROWS / 512);
  for (int rr = 0; rr < NROWS / 512; ++rr) {
    const int r = rbase + rr;
    if (!(idx[r] & 0x80000000u)) continue;
    const int bh = r >> 11;
    const int i = r & (N_ - 1);
    const float* qr = q + (size_t)r * D_;
    const float* kb = k + (size_t)bh * N_ * D_;
    if (tid < D_) qd[tid] = (double)qr[tid];
    __syncthreads();
    double qsqd = 0.0;
    for (int d = 0; d < D_; ++d) qsqd = fma(qd[d], qd[d], qsqd);
    double bbest = 1e300;
    int bjj = 0;
    for (int j = tid; j <= i; j += 256) {
      const float* kr = kb + (size_t)j * D_;
      double a0 = 0, a1 = 0, s0 = 0, s1 = 0;
      for (int d = 0; d < D_; d += 2) {
        const double k0 = (double)kr[d], k1 = (double)kr[d + 1];
        a0 = fma(qd[d], k0, a0);  a1 = fma(qd[d + 1], k1, a1);
        s0 = fma(k0, k0, s0);     s1 = fma(k1, k1, s1);
      }
      const double raw = (qsqd + (s0 + s1)) - 2.0 * (a0 + a1);
      const double d2 = raw > 0.0 ? raw : 0.0;
      if (d2 < bbest) { bbest = d2; bjj = j; }
    }
    sd[tid] = bbest; sj[tid] = bjj;
    __syncthreads();
    for (int s = 128; s > 0; s >>= 1) {
      if (tid < s) {
        const double ob = sd[tid + s]; const int oj = sj[tid + s];
        if (ob < sd[tid] || (ob == sd[tid] && oj < sj[tid])) {
          sd[tid] = ob; sj[tid] = oj;
        }
      }
      __syncthreads();
    }
    if (tid == 0) idx[r] = (u32)sj[0];
    __syncthreads();
  }
}

// ---------------------------------------------------------------------------
// Gather: out[r, :] = v[bh, idx[r] & 0xFFFF, :]  (float4-vectorized)
// ---------------------------------------------------------------------------
__global__ __launch_bounds__(256) void gather_v(
    const float* __restrict__ v, const u32* __restrict__ idx,
    float* __restrict__ out)
{
  const int g = blockIdx.x * 256 + threadIdx.x;
  const int r = g >> 4, c = g & 15;
  const u32 j = idx[r] & 0xFFFFu;
  const int bh = r >> 11;
  const float4 val = ((const float4*)(v + ((size_t)bh * N_ + j) * D_))[c];
  ((float4*)(out + (size_t)r * D_))[c] = val;
}

// ---------------------------------------------------------------------------
extern "C" void kernel_launch(void* const* d_in, const int* in_sizes, int n_in,
                              void* d_out, int out_size, void* d_ws,
                              size_t ws_size, hipStream_t stream) {
  const float* q = (const float*)d_in[0];
  const float* k = (const float*)d_in[1];
  const float* v = (const float*)d_in[2];
  float* out = (float*)d_out;

  // Segment scratch lives in d_out (6 MB of 8 MB; fully overwritten by
  // gather_v). ws: [count u32 | pad to 64B | idx (128KB) | list (128KB)].
  u64* bestseg = (u64*)d_out;                                // 4 MB
  u32* secseg = (u32*)(bestseg + (size_t)NROWS * NSEG);      // 2 MB
  u32* count = (u32*)d_ws;
  u32* idx = (u32*)((char*)d_ws + 64);
  u32* flaglist = idx + NROWS;
  const int use_list = (ws_size >= 64 + 2 * (size_t)NROWS * 4) ? 1 : 0;

  hipMemsetAsync(count, 0, 4, stream);

  dim3 g1(NACT, BH_);
  phase1_argmin<<<g1, TI, 0, stream>>>(q, k, bestseg, secseg);
  combine_segs<<<NROWS / 256, 256, 0, stream>>>(bestseg, secseg, idx,
                                                flaglist, count, use_list);
  if (use_list)
    exact_fix_list<<<64, 256, 0, stream>>>(q, k, idx, flaglist, count);
  else
    exact_fix_scan<<<512, 256, 0, stream>>>(q, k, idx);
  gather_v<<<(NROWS * (D_ / 4)) / 256, 256, 0, stream>>>(v, idx, out);
}

// Round 3
// 72.257 us; speedup vs baseline: 3.9532x; 1.7116x over previous
//
#include <hip/hip_runtime.h>
#include <stdint.h>

// Problem constants (B=2, H=8, N=2048, D=64, f32 in/out).
#define B_ 2
#define H_ 8
#define N_ 2048
#define D_ 64
#define BH_ (B_ * H_)
#define NROWS (BH_ * N_)      // 32768
#define TJ 128                // j-segment width
#define NSEG (N_ / TJ)        // 16
#define NACT 272              // triangular (it,jt) tiles: sum_{it=0}^{31}(it/2+1)
#define EPSF 8e-3f            // margin below which we re-resolve the row in f64

using u64 = unsigned long long;
using u32 = unsigned int;
typedef __attribute__((ext_vector_type(8))) short short8;   // 8 bf16
typedef __attribute__((ext_vector_type(4))) float f32x4;

// ---------------------------------------------------------------------------
// Phase 1 (MFMA): per (row, j-segment) argmin of d2 = max(|q|^2+|k|^2-2q.k,0).
// Block = 256 thr = 4 waves; i-tile = 64 rows (wave w owns 16 rows);
// j-seg = 128 staged in LDS as bf16 hi/lo (split-bf16: dot = hi*hi+hi*lo+lo*hi,
// err ~1e-4 << EPSF/2). Per 16x16 j-subtile: 6x mfma_f32_16x16x32_bf16.
// C/D layout (m89): col=lane&15, row=(lane>>4)*4+reg. A/B: row/col=lane&15,
// k=(lane>>4)*8+e. LDS k-tile XOR-swizzled (byte ^= (j&7)<<4) to spread
// ds_read_b128 across banks. best packed (f32bits<<32)|j: u64-min == (min d2,
// first index) matching np.argmax first-occurrence; per-slot second tracked
// for the EPSF flag.
// ---------------------------------------------------------------------------
__global__ __launch_bounds__(256) void phase1_mfma(
    const float* __restrict__ q, const float* __restrict__ k,
    u64* __restrict__ bestseg, u32* __restrict__ secseg)
{
  // triangular decode: i-tile it (64 rows), jt in [0, it/2]
  int x = (int)blockIdx.x;
  int it = 0, cnt = 1;
  while (x >= cnt) { x -= cnt; ++it; cnt = (it >> 1) + 1; }
  const int jt = x;
  const int bh = blockIdx.y;
  const int i0 = it * 64, j0 = jt * TJ;

  __shared__ __align__(16) char lds_khi[TJ * 128];  // 16KB  [j][kg]*16B ^swz
  __shared__ __align__(16) char lds_klo[TJ * 128];  // 16KB
  __shared__ float kpart[8 * TJ];                   // 4KB   [kg][j]
  __shared__ float ksq_s[TJ];

  const int tid = threadIdx.x;
  const int lane = tid & 63, w = tid >> 6;
  const int g = lane >> 4, c0 = lane & 15, s7 = lane & 7;
  const float* kb = k + (size_t)bh * N_ * D_;

  // ---- stage k-seg: f32 -> bf16 hi/lo into LDS (+ |k|^2 partials) ----
  #pragma unroll
  for (int iter = 0; iter < 4; ++iter) {
    const int c = tid + iter * 256;
    const int j = c & 127, kg = c >> 7;
    const float* kp = kb + (size_t)(j0 + j) * D_ + kg * 8;
    const float4 f0 = *(const float4*)kp;
    const float4 f1 = *(const float4*)(kp + 4);
    const float vv[8] = {f0.x, f0.y, f0.z, f0.w, f1.x, f1.y, f1.z, f1.w};
    u32 hw[4], lw[4];
    float ps = 0.f;
    #pragma unroll
    for (int e = 0; e < 4; ++e) {
      const float va = vv[2 * e], vb = vv[2 * e + 1];
      ps = fmaf(va, va, ps); ps = fmaf(vb, vb, ps);
      const u32 ha = __float_as_uint(va) & 0xFFFF0000u;
      const u32 hb = __float_as_uint(vb) & 0xFFFF0000u;
      hw[e] = (ha >> 16) | hb;
      const u32 la = __float_as_uint(va - __uint_as_float(ha));
      const u32 lb = __float_as_uint(vb - __uint_as_float(hb));
      lw[e] = (la >> 16) | (lb & 0xFFFF0000u);
    }
    const u32 off = (u32)(j * 128 + kg * 16) ^ ((u32)(j & 7) << 4);
    *(uint4*)(lds_khi + off) = make_uint4(hw[0], hw[1], hw[2], hw[3]);
    *(uint4*)(lds_klo + off) = make_uint4(lw[0], lw[1], lw[2], lw[3]);
    kpart[kg * TJ + j] = ps;
  }

  // ---- stage q: A-fragments (hi/lo) in regs + |q|^2 via shfl ----
  const int iminw = i0 + w * 16;
  const int imaxw = iminw + 15;
  const float* qrow = q + ((size_t)bh * N_ + iminw + c0) * D_ + g * 8;
  short8 ah0, al0, ah1, al1;
  float qpart = 0.f;
  {
    const float4 f0 = *(const float4*)(qrow);
    const float4 f1 = *(const float4*)(qrow + 4);
    const float vv[8] = {f0.x, f0.y, f0.z, f0.w, f1.x, f1.y, f1.z, f1.w};
    #pragma unroll
    for (int e = 0; e < 8; ++e) {
      const float v = vv[e];
      qpart = fmaf(v, v, qpart);
      const u32 hb = __float_as_uint(v) & 0xFFFF0000u;
      ah0[e] = (short)(hb >> 16);
      al0[e] = (short)(__float_as_uint(v - __uint_as_float(hb)) >> 16);
    }
  }
  {
    const float4 f0 = *(const float4*)(qrow + 32);
    const float4 f1 = *(const float4*)(qrow + 36);
    const float vv[8] = {f0.x, f0.y, f0.z, f0.w, f1.x, f1.y, f1.z, f1.w};
    #pragma unroll
    for (int e = 0; e < 8; ++e) {
      const float v = vv[e];
      qpart = fmaf(v, v, qpart);
      const u32 hb = __float_as_uint(v) & 0xFFFF0000u;
      ah1[e] = (short)(hb >> 16);
      al1[e] = (short)(__float_as_uint(v - __uint_as_float(hb)) >> 16);
    }
  }
  float qs = qpart;
  qs += __shfl_xor(qs, 16);
  qs += __shfl_xor(qs, 32);        // lane now has qsq of row (lane&15)
  float qsqr[4];
  #pragma unroll
  for (int reg = 0; reg < 4; ++reg) qsqr[reg] = __shfl(qs, g * 4 + reg);

  __syncthreads();
  if (tid < TJ) {                  // |k|^2 per row
    float s = 0.f;
    #pragma unroll
    for (int kg = 0; kg < 8; ++kg) s += kpart[kg * TJ + tid];
    ksq_s[tid] = s;
  }
  __syncthreads();

  // ---- main loop over 16-wide j-subtiles ----
  u64 best[4] = {~0ull, ~0ull, ~0ull, ~0ull};
  u32 sec[4] = {0xFFFFFFFFu, 0xFFFFFFFFu, 0xFFFFFFFFu, 0xFFFFFFFFu};
  const int irow0 = iminw + g * 4;

  for (int js = 0; js < 8; ++js) {
    const int jbase = j0 + js * 16;
    if (jbase > imaxw) break;      // uniform per wave
    const int relj = js * 16 + c0;
    const u32 offA = (u32)(relj * 128 + g * 16) ^ ((u32)s7 << 4);        // h=0
    const u32 offB = (u32)(relj * 128 + (4 + g) * 16) ^ ((u32)s7 << 4);  // h=1
    const short8 bh0 = *(const short8*)(lds_khi + offA);
    const short8 bh1 = *(const short8*)(lds_khi + offB);
    const short8 bl0 = *(const short8*)(lds_klo + offA);
    const short8 bl1 = *(const short8*)(lds_klo + offB);
    f32x4 acc = {0.f, 0.f, 0.f, 0.f};
    acc = __builtin_amdgcn_mfma_f32_16x16x32_bf16(ah0, bh0, acc, 0, 0, 0);
    acc = __builtin_amdgcn_mfma_f32_16x16x32_bf16(ah1, bh1, acc, 0, 0, 0);
    acc = __builtin_amdgcn_mfma_f32_16x16x32_bf16(ah0, bl0, acc, 0, 0, 0);
    acc = __builtin_amdgcn_mfma_f32_16x16x32_bf16(ah1, bl1, acc, 0, 0, 0);
    acc = __builtin_amdgcn_mfma_f32_16x16x32_bf16(al0, bh0, acc, 0, 0, 0);
    acc = __builtin_amdgcn_mfma_f32_16x16x32_bf16(al1, bh1, acc, 0, 0, 0);

    const float ks = ksq_s[relj];
    const int jcol = jbase + c0;
    if (jbase + 15 <= iminw) {     // fully-causal fast path
      #pragma unroll
      for (int reg = 0; reg < 4; ++reg) {
        const float d2 = fmaxf(fmaf(-2.f, acc[reg], qsqr[reg] + ks), 0.f);
        const u64 cand = ((u64)__float_as_uint(d2) << 32) | (u32)jcol;
        if (cand < best[reg]) {
          sec[reg] = min(sec[reg], (u32)(best[reg] >> 32)); best[reg] = cand;
        } else sec[reg] = min(sec[reg], (u32)(cand >> 32));
      }
    } else {                       // diagonal subtile: per-element mask
      #pragma unroll
      for (int reg = 0; reg < 4; ++reg) {
        const float d2 = fmaxf(fmaf(-2.f, acc[reg], qsqr[reg] + ks), 0.f);
        u64 cand = ((u64)__float_as_uint(d2) << 32) | (u32)jcol;
        if (jcol > irow0 + reg) cand = ~0ull;
        if (cand < best[reg]) {
          sec[reg] = min(sec[reg], (u32)(best[reg] >> 32)); best[reg] = cand;
        } else sec[reg] = min(sec[reg], (u32)(cand >> 32));
      }
    }
  }

  // ---- reduce over the 16 col-slots (lanes sharing g hold the same rows) ----
  #pragma unroll
  for (int m = 1; m < 16; m <<= 1) {
    #pragma unroll
    for (int reg = 0; reg < 4; ++reg) {
      const u64 ob = (u64)__shfl_xor((long long)best[reg], m);
      const u32 os = (u32)__shfl_xor((int)sec[reg], m);
      const u32 loser = (ob < best[reg]) ? (u32)(best[reg] >> 32)
                                         : (u32)(ob >> 32);
      best[reg] = (ob < best[reg]) ? ob : best[reg];
      sec[reg] = min(min(sec[reg], os), loser);
    }
  }
  if (c0 == 0) {
    const size_t rbase = (size_t)bh * N_ + irow0;
    #pragma unroll
    for (int reg = 0; reg < 4; ++reg) {
      bestseg[(size_t)jt * NROWS + rbase + reg] = best[reg];
      secseg[(size_t)jt * NROWS + rbase + reg] = sec[reg];
    }
  }
}

// ---------------------------------------------------------------------------
// Combine per-segment results (segments s <= i>>7 all written). Flag rows
// whose best/second margin < EPSF into a compacted list.
// ---------------------------------------------------------------------------
__global__ __launch_bounds__(256) void combine_segs(
    const u64* __restrict__ bestseg, const u32* __restrict__ secseg,
    u32* __restrict__ idx, u32* __restrict__ flaglist, u32* __restrict__ count,
    int use_list)
{
  const int r = blockIdx.x * 256 + threadIdx.x;
  if (r >= NROWS) return;
  const int i = r & (N_ - 1);
  const int smax = i >> 7;
  u64 b0 = ~0ull;
  u32 s1 = 0xFFFFFFFFu;
  int sstar = 0;
  for (int s = 0; s <= smax; ++s) {
    const u64 kk = bestseg[(size_t)s * NROWS + r];
    if (kk < b0) { s1 = min(s1, (u32)(b0 >> 32)); b0 = kk; sstar = s; }
    else         { s1 = min(s1, (u32)(kk >> 32)); }
  }
  s1 = min(s1, secseg[(size_t)sstar * NROWS + r]);
  const float best = __uint_as_float((u32)(b0 >> 32));
  const float secf = __uint_as_float(s1);        // may be +inf / NaN
  const bool flag = (secf - best) < EPSF;        // NaN -> false
  if (use_list) {
    idx[r] = (u32)(b0 & 0xFFFFu);
    if (flag) { const u32 p = atomicAdd(count, 1u); flaglist[p] = r; }
  } else {
    idx[r] = (u32)(b0 & 0xFFFFu) | (flag ? 0x80000000u : 0u);
  }
}

// ---------------------------------------------------------------------------
// Exact f64 re-resolution of near-tie rows — compacted-list variant.
// ---------------------------------------------------------------------------
__global__ __launch_bounds__(256) void exact_fix_list(
    const float* __restrict__ q, const float* __restrict__ k,
    u32* __restrict__ idx, const u32* __restrict__ flaglist,
    const u32* __restrict__ count)
{
  __shared__ double qd[D_];
  __shared__ double sd[256];
  __shared__ int sj[256];
  const int tid = threadIdx.x;
  const int cnt = (int)count[0];
  for (int li = blockIdx.x; li < cnt; li += (int)gridDim.x) {
    const int r = (int)flaglist[li];
    const int bh = r >> 11;
    const int i = r & (N_ - 1);
    const float* qr = q + (size_t)r * D_;
    const float* kb = k + (size_t)bh * N_ * D_;
    if (tid < D_) qd[tid] = (double)qr[tid];
    __syncthreads();
    double qsqd = 0.0;
    for (int d = 0; d < D_; ++d) qsqd = fma(qd[d], qd[d], qsqd);
    double bbest = 1e300;
    int bjj = 0;
    for (int j = tid; j <= i; j += 256) {
      const float* kr = kb + (size_t)j * D_;
      double a0 = 0, a1 = 0, s0 = 0, s1 = 0;
      for (int d = 0; d < D_; d += 2) {
        const double k0 = (double)kr[d], k1 = (double)kr[d + 1];
        a0 = fma(qd[d], k0, a0);  a1 = fma(qd[d + 1], k1, a1);
        s0 = fma(k0, k0, s0);     s1 = fma(k1, k1, s1);
      }
      const double raw = (qsqd + (s0 + s1)) - 2.0 * (a0 + a1);
      const double d2 = raw > 0.0 ? raw : 0.0;
      if (d2 < bbest) { bbest = d2; bjj = j; }   // ascending j -> first on tie
    }
    sd[tid] = bbest; sj[tid] = bjj;
    __syncthreads();
    for (int s = 128; s > 0; s >>= 1) {
      if (tid < s) {
        const double ob = sd[tid + s]; const int oj = sj[tid + s];
        if (ob < sd[tid] || (ob == sd[tid] && oj < sj[tid])) {
          sd[tid] = ob; sj[tid] = oj;
        }
      }
      __syncthreads();
    }
    if (tid == 0) idx[r] = (u32)sj[0];
    __syncthreads();
  }
}

// Legacy scan variant (used only if ws is too small for the list).
__global__ __launch_bounds__(256) void exact_fix_scan(
    const float* __restrict__ q, const float* __restrict__ k,
    u32* __restrict__ idx)
{
  __shared__ double qd[D_];
  __shared__ double sd[256];
  __shared__ int sj[256];
  const int tid = threadIdx.x;
  const int rbase = blockIdx.x * (NROWS / 512);
  for (int rr = 0; rr < NROWS / 512; ++rr) {
    const int r = rbase + rr;
    if (!(idx[r] & 0x80000000u)) continue;
    const int bh = r >> 11;
    const int i = r & (N_ - 1);
    const float* qr = q + (size_t)r * D_;
    const float* kb = k + (size_t)bh * N_ * D_;
    if (tid < D_) qd[tid] = (double)qr[tid];
    __syncthreads();
    double qsqd = 0.0;
    for (int d = 0; d < D_; ++d) qsqd = fma(qd[d], qd[d], qsqd);
    double bbest = 1e300;
    int bjj = 0;
    for (int j = tid; j <= i; j += 256) {
      const float* kr = kb + (size_t)j * D_;
      double a0 = 0, a1 = 0, s0 = 0, s1 = 0;
      for (int d = 0; d < D_; d += 2) {
        const double k0 = (double)kr[d], k1 = (double)kr[d + 1];
        a0 = fma(qd[d], k0, a0);  a1 = fma(qd[d + 1], k1, a1);
        s0 = fma(k0, k0, s0);     s1 = fma(k1, k1, s1);
      }
      const double raw = (qsqd + (s0 + s1)) - 2.0 * (a0 + a1);
      const double d2 = raw > 0.0 ? raw : 0.0;
      if (d2 < bbest) { bbest = d2; bjj = j; }
    }
    sd[tid] = bbest; sj[tid] = bjj;
    __syncthreads();
    for (int s = 128; s > 0; s >>= 1) {
      if (tid < s) {
        const double ob = sd[tid + s]; const int oj = sj[tid + s];
        if (ob < sd[tid] || (ob == sd[tid] && oj < sj[tid])) {
          sd[tid] = ob; sj[tid] = oj;
        }
      }
      __syncthreads();
    }
    if (tid == 0) idx[r] = (u32)sj[0];
    __syncthreads();
  }
}

// ---------------------------------------------------------------------------
// Gather: out[r, :] = v[bh, idx[r] & 0xFFFF, :]  (float4-vectorized)
// ---------------------------------------------------------------------------
__global__ __launch_bounds__(256) void gather_v(
    const float* __restrict__ v, const u32* __restrict__ idx,
    float* __restrict__ out)
{
  const int gidx = blockIdx.x * 256 + threadIdx.x;
  const int r = gidx >> 4, c = gidx & 15;
  const u32 j = idx[r] & 0xFFFFu;
  const int bh = r >> 11;
  const float4 val = ((const float4*)(v + ((size_t)bh * N_ + j) * D_))[c];
  ((float4*)(out + (size_t)r * D_))[c] = val;
}

// ---------------------------------------------------------------------------
extern "C" void kernel_launch(void* const* d_in, const int* in_sizes, int n_in,
                              void* d_out, int out_size, void* d_ws,
                              size_t ws_size, hipStream_t stream) {
  const float* q = (const float*)d_in[0];
  const float* k = (const float*)d_in[1];
  const float* v = (const float*)d_in[2];
  float* out = (float*)d_out;

  // Segment scratch in d_out (6 MB of 8 MB; fully overwritten by gather_v).
  // ws: [count u32 | pad 64B | idx (128KB) | list (128KB)].
  u64* bestseg = (u64*)d_out;                                // 4 MB
  u32* secseg = (u32*)(bestseg + (size_t)NROWS * NSEG);      // 2 MB
  u32* count = (u32*)d_ws;
  u32* idx = (u32*)((char*)d_ws + 64);
  u32* flaglist = idx + NROWS;
  const int use_list = (ws_size >= 64 + 2 * (size_t)NROWS * 4) ? 1 : 0;

  hipMemsetAsync(count, 0, 4, stream);

  phase1_mfma<<<dim3(NACT, BH_), 256, 0, stream>>>(q, k, bestseg, secseg);
  combine_segs<<<NROWS / 256, 256, 0, stream>>>(bestseg, secseg, idx,
                                                flaglist, count, use_list);
  if (use_list)
    exact_fix_list<<<64, 256, 0, stream>>>(q, k, idx, flaglist, count);
  else
    exact_fix_scan<<<512, 256, 0, stream>>>(q, k, idx);
  gather_v<<<(NROWS * (D_ / 4)) / 256, 256, 0, stream>>>(v, idx, out);
}

// Round 4
// 68.347 us; speedup vs baseline: 4.1794x; 1.0572x over previous
//
#include <hip/hip_runtime.h>
#include <stdint.h>

// Problem constants (B=2, H=8, N=2048, D=64, f32 in/out).
#define B_ 2
#define H_ 8
#define N_ 2048
#define D_ 64
#define BH_ (B_ * H_)
#define NROWS (BH_ * N_)      // 32768
#define TJ 128                // j-segment width
#define NSEG (N_ / TJ)        // 16
#define IT 128                // i-tile rows per block (4 waves x 32 rows)
#define NACT 136              // per-bh active (it,jt): sum_{it=0}^{15}(it+1)
#define NBLK (NACT * BH_)     // 2176 = 8 * 272  (XCD-swizzle friendly)
#define EPSF 8e-3f            // margin below which we re-resolve the row in f64

using u64 = unsigned long long;
using u32 = unsigned int;
typedef __attribute__((ext_vector_type(8))) short short8;   // 8 bf16
typedef __attribute__((ext_vector_type(4))) float f32x4;

// async global->LDS, 16B per lane; LDS dest = wave-uniform base + lane*16.
#define GL16(gsrc, ldst) __builtin_amdgcn_global_load_lds( \
    (const __attribute__((address_space(1))) unsigned int*)(gsrc), \
    (__attribute__((address_space(3))) unsigned int*)(ldst), 16, 0, 0)

// ---------------------------------------------------------------------------
// Prep: split k (f32) into bf16 hi/lo, written in the PRE-SWIZZLED per-seg
// LDS tile image (so phase1<1> can global_load_lds it linearly), plus
// ksq[bh][j]. One thread per (row, 8-elem k-group).
// ---------------------------------------------------------------------------
__global__ __launch_bounds__(256) void prep_split(
    const float* __restrict__ k, char* __restrict__ khi_g,
    char* __restrict__ klo_g, float* __restrict__ ksq_g)
{
  const int t = (int)blockIdx.x * 256 + threadIdx.x;  // NROWS*8 total
  const int r = t >> 3, kg = t & 7;
  const int jp = r & (TJ - 1);                        // row within segment
  const float* kp = k + (size_t)r * D_ + kg * 8;
  const float4 f0 = *(const float4*)kp;
  const float4 f1 = *(const float4*)(kp + 4);
  const float vv[8] = {f0.x, f0.y, f0.z, f0.w, f1.x, f1.y, f1.z, f1.w};
  u32 hw[4], lw[4];
  float ps = 0.f;
  #pragma unroll
  for (int e = 0; e < 4; ++e) {
    const float va = vv[2 * e], vb = vv[2 * e + 1];
    ps = fmaf(va, va, ps); ps = fmaf(vb, vb, ps);
    const u32 ha = __float_as_uint(va) & 0xFFFF0000u;
    const u32 hb = __float_as_uint(vb) & 0xFFFF0000u;
    hw[e] = (ha >> 16) | hb;
    const u32 la = __float_as_uint(va - __uint_as_float(ha));
    const u32 lb = __float_as_uint(vb - __uint_as_float(hb));
    lw[e] = (la >> 16) | (lb & 0xFFFF0000u);
  }
  const u32 off = (u32)(jp * 128 + kg * 16) ^ ((u32)(jp & 7) << 4);
  const size_t tile = (size_t)(r >> 7) * 16384;       // (bh*16+jt)*16KB
  *(uint4*)(khi_g + tile + off) = make_uint4(hw[0], hw[1], hw[2], hw[3]);
  *(uint4*)(klo_g + tile + off) = make_uint4(lw[0], lw[1], lw[2], lw[3]);
  float ssum = ps;                                    // |k_row|^2 over kg octet
  ssum += __shfl_xor(ssum, 1);
  ssum += __shfl_xor(ssum, 2);
  ssum += __shfl_xor(ssum, 4);
  if (kg == 0) ksq_g[r] = ssum;
}

// ---------------------------------------------------------------------------
// Phase 1 (MFMA): per (row, j-segment) argmin of d2 = max(|q|^2+|k|^2-2q.k,0).
// Block = 4 waves; i-tile = 128 rows (wave w owns 32 rows = 2 A-frag sets);
// j-seg = 128 in LDS as bf16 hi/lo (dot = hi*hi+hi*lo+lo*hi, err ~1e-4 <<
// EPSF/2). PRE=1: stage via global_load_lds from prep's pre-swizzled tiles;
// PRE=0: convert in-kernel (identical numerics). 12 MFMA per 4 ds_read_b128.
// best packed (f32bits<<32)|j: u64-min == (min d2, first index) matching
// np.argmax first-occurrence; per-slot second tracked for the EPSF flag.
// Grid flattened + XCD-swizzled: each XCD gets 2 consecutive bh.
// ---------------------------------------------------------------------------
template <int PRE>
__global__ __launch_bounds__(256) void phase1(
    const float* __restrict__ q, const float* __restrict__ k,
    const char* __restrict__ khi_g, const char* __restrict__ klo_g,
    const float* __restrict__ ksq_g,
    u64* __restrict__ bestseg, u32* __restrict__ secseg,
    u32* __restrict__ count)
{
  if (blockIdx.x == 0 && threadIdx.x == 0) count[0] = 0;
  const int b = (int)blockIdx.x;
  const int orig = (b & 7) * (NBLK / 8) + (b >> 3);   // XCD swizzle (bijective)
  const int bh = orig / NACT;
  const int x = orig - bh * NACT;
  int it = 0;
  while ((it + 1) * (it + 2) / 2 <= x) ++it;          // triangular decode
  const int jt = x - it * (it + 1) / 2;
  const int i0 = it * IT, j0 = jt * TJ;
  const bool diag = (jt == it);

  __shared__ __align__(16) char lds_khi[TJ * 128];    // 16KB swizzled tile
  __shared__ __align__(16) char lds_klo[TJ * 128];    // 16KB
  __shared__ float kpart[8 * TJ];                     // 4KB (conv path only)
  __shared__ float ksq_s[TJ];

  const int tid = threadIdx.x;
  const int lane = tid & 63, w = tid >> 6;
  const int g = lane >> 4, c0 = lane & 15, s7 = lane & 7;
  const float* kb = k + (size_t)bh * N_ * D_;

  // ---- k staging ----
  if constexpr (PRE) {
    const size_t tile = ((size_t)bh * NSEG + jt) * 16384;
    const char* srcH = khi_g + tile + (size_t)(w * 4096 + lane * 16);
    const char* srcL = klo_g + tile + (size_t)(w * 4096 + lane * 16);
    char* dH = lds_khi + w * 4096 + lane * 16;
    char* dL = lds_klo + w * 4096 + lane * 16;
    #pragma unroll
    for (int rnd = 0; rnd < 4; ++rnd) {
      GL16(srcH + rnd * 1024, dH + rnd * 1024);
      GL16(srcL + rnd * 1024, dL + rnd * 1024);
    }
    if (tid < TJ) ksq_s[tid] = ksq_g[(size_t)bh * N_ + j0 + tid];
  } else {
    #pragma unroll
    for (int iter = 0; iter < 4; ++iter) {
      const int c = tid + iter * 256;
      const int j = c & 127, kg = c >> 7;
      const float* kp = kb + (size_t)(j0 + j) * D_ + kg * 8;
      const float4 f0 = *(const float4*)kp;
      const float4 f1 = *(const float4*)(kp + 4);
      const float vv[8] = {f0.x, f0.y, f0.z, f0.w, f1.x, f1.y, f1.z, f1.w};
      u32 hw[4], lw[4];
      float ps = 0.f;
      #pragma unroll
      for (int e = 0; e < 4; ++e) {
        const float va = vv[2 * e], vb = vv[2 * e + 1];
        ps = fmaf(va, va, ps); ps = fmaf(vb, vb, ps);
        const u32 ha = __float_as_uint(va) & 0xFFFF0000u;
        const u32 hb2 = __float_as_uint(vb) & 0xFFFF0000u;
        hw[e] = (ha >> 16) | hb2;
        const u32 la = __float_as_uint(va - __uint_as_float(ha));
        const u32 lb = __float_as_uint(vb - __uint_as_float(hb2));
        lw[e] = (la >> 16) | (lb & 0xFFFF0000u);
      }
      const u32 off = (u32)(j * 128 + kg * 16) ^ ((u32)(j & 7) << 4);
      *(uint4*)(lds_khi + off) = make_uint4(hw[0], hw[1], hw[2], hw[3]);
      *(uint4*)(lds_klo + off) = make_uint4(lw[0], lw[1], lw[2], lw[3]);
      kpart[kg * TJ + j] = ps;
    }
  }

  // ---- q: 2 A-frag sets (rows iminw+s*16+c0) hi/lo + |q|^2 via shfl ----
  const int iminw = i0 + w * 32;
  short8 ah[2][2], al[2][2];
  float qsqr[2][4];
  #pragma unroll
  for (int s = 0; s < 2; ++s) {
    const float* qrow =
        q + ((size_t)bh * N_ + iminw + s * 16 + c0) * D_ + g * 8;
    float qpart = 0.f;
    #pragma unroll
    for (int h = 0; h < 2; ++h) {
      const float4 f0 = *(const float4*)(qrow + h * 32);
      const float4 f1 = *(const float4*)(qrow + h * 32 + 4);
      const float vv[8] = {f0.x, f0.y, f0.z, f0.w, f1.x, f1.y, f1.z, f1.w};
      #pragma unroll
      for (int e = 0; e < 8; ++e) {
        const float v = vv[e];
        qpart = fmaf(v, v, qpart);
        const u32 hb = __float_as_uint(v) & 0xFFFF0000u;
        ah[s][h][e] = (short)(hb >> 16);
        al[s][h][e] = (short)(__float_as_uint(v - __uint_as_float(hb)) >> 16);
      }
    }
    float qs = qpart;
    qs += __shfl_xor(qs, 16);
    qs += __shfl_xor(qs, 32);          // lane holds qsq of row (lane&15)
    #pragma unroll
    for (int reg = 0; reg < 4; ++reg) qsqr[s][reg] = __shfl(qs, g * 4 + reg);
  }

  __syncthreads();
  if constexpr (!PRE) {
    if (tid < TJ) {
      float ssum = 0.f;
      #pragma unroll
      for (int kg = 0; kg < 8; ++kg) ssum += kpart[kg * TJ + tid];
      ksq_s[tid] = ssum;
    }
    __syncthreads();
  }

  // ---- main loop over 16-wide j-subtiles ----
  u64 best[2][4];
  u32 sec[2][4];
  #pragma unroll
  for (int s = 0; s < 2; ++s)
    #pragma unroll
    for (int r2 = 0; r2 < 4; ++r2) { best[s][r2] = ~0ull; sec[s][r2] = 0xFFFFFFFFu; }

  const int jsmax = diag ? (2 * w + 1) : 7;
  for (int js = 0; js <= jsmax; ++js) {
    const int relj = js * 16 + c0;
    const u32 offA = (u32)(relj * 128 + g * 16) ^ ((u32)s7 << 4);        // h=0
    const u32 offB = (u32)(relj * 128 + (4 + g) * 16) ^ ((u32)s7 << 4);  // h=1
    const short8 kh0 = *(const short8*)(lds_khi + offA);
    const short8 kh1 = *(const short8*)(lds_khi + offB);
    const short8 kl0 = *(const short8*)(lds_klo + offA);
    const short8 kl1 = *(const short8*)(lds_klo + offB);
    const float ks = ksq_s[relj];
    const int jcol = j0 + relj;
    #pragma unroll
    for (int s = 0; s < 2; ++s) {
      if (diag && js > 2 * w + s) continue;   // set above causal range
      f32x4 acc = {0.f, 0.f, 0.f, 0.f};
      acc = __builtin_amdgcn_mfma_f32_16x16x32_bf16(ah[s][0], kh0, acc, 0, 0, 0);
      acc = __builtin_amdgcn_mfma_f32_16x16x32_bf16(ah[s][1], kh1, acc, 0, 0, 0);
      acc = __builtin_amdgcn_mfma_f32_16x16x32_bf16(ah[s][0], kl0, acc, 0, 0, 0);
      acc = __builtin_amdgcn_mfma_f32_16x16x32_bf16(ah[s][1], kl1, acc, 0, 0, 0);
      acc = __builtin_amdgcn_mfma_f32_16x16x32_bf16(al[s][0], kh0, acc, 0, 0, 0);
      acc = __builtin_amdgcn_mfma_f32_16x16x32_bf16(al[s][1], kh1, acc, 0, 0, 0);
      const bool dsub = diag && (js == 2 * w + s);  // diagonal subtile
      const int irow0 = iminw + s * 16 + g * 4;
      #pragma unroll
      for (int reg = 0; reg < 4; ++reg) {
        const float d2 = fmaxf(fmaf(-2.f, acc[reg], qsqr[s][reg] + ks), 0.f);
        u64 cand = ((u64)__float_as_uint(d2) << 32) | (u32)jcol;
        if (dsub && jcol > irow0 + reg) cand = ~0ull;
        if (cand < best[s][reg]) {
          sec[s][reg] = min(sec[s][reg], (u32)(best[s][reg] >> 32));
          best[s][reg] = cand;
        } else sec[s][reg] = min(sec[s][reg], (u32)(cand >> 32));
      }
    }
  }

  // ---- reduce over the 16 col-slots ----
  #pragma unroll
  for (int m = 1; m < 16; m <<= 1) {
    #pragma unroll
    for (int s = 0; s < 2; ++s)
      #pragma unroll
      for (int reg = 0; reg < 4; ++reg) {
        const u64 ob = (u64)__shfl_xor((long long)best[s][reg], m);
        const u32 os = (u32)__shfl_xor((int)sec[s][reg], m);
        const u32 loser = (ob < best[s][reg]) ? (u32)(best[s][reg] >> 32)
                                              : (u32)(ob >> 32);
        best[s][reg] = (ob < best[s][reg]) ? ob : best[s][reg];
        sec[s][reg] = min(min(sec[s][reg], os), loser);
      }
  }
  if (c0 == 0) {
    #pragma unroll
    for (int s = 0; s < 2; ++s) {
      const size_t rbase = (size_t)bh * N_ + iminw + s * 16 + g * 4;
      #pragma unroll
      for (int reg = 0; reg < 4; ++reg) {
        bestseg[(size_t)jt * NROWS + rbase + reg] = best[s][reg];
        secseg[(size_t)jt * NROWS + rbase + reg] = sec[s][reg];
      }
    }
  }
}

// ---------------------------------------------------------------------------
// Combine per-segment results (segments s <= i>>7 all written). Flag rows
// whose best/second margin < EPSF into a compacted list.
// ---------------------------------------------------------------------------
__global__ __launch_bounds__(256) void combine_segs(
    const u64* __restrict__ bestseg, const u32* __restrict__ secseg,
    u32* __restrict__ idx, u32* __restrict__ flaglist, u32* __restrict__ count,
    int use_list)
{
  const int r = blockIdx.x * 256 + threadIdx.x;
  if (r >= NROWS) return;
  const int i = r & (N_ - 1);
  const int smax = i >> 7;
  u64 b0 = ~0ull;
  u32 s1 = 0xFFFFFFFFu;
  int sstar = 0;
  for (int s = 0; s <= smax; ++s) {
    const u64 kk = bestseg[(size_t)s * NROWS + r];
    if (kk < b0) { s1 = min(s1, (u32)(b0 >> 32)); b0 = kk; sstar = s; }
    else         { s1 = min(s1, (u32)(kk >> 32)); }
  }
  s1 = min(s1, secseg[(size_t)sstar * NROWS + r]);
  const float best = __uint_as_float((u32)(b0 >> 32));
  const float secf = __uint_as_float(s1);        // may be +inf / NaN
  const bool flag = (secf - best) < EPSF;        // NaN -> false
  if (use_list) {
    idx[r] = (u32)(b0 & 0xFFFFu);
    if (flag) { const u32 p = atomicAdd(count, 1u); flaglist[p] = r; }
  } else {
    idx[r] = (u32)(b0 & 0xFFFFu) | (flag ? 0x80000000u : 0u);
  }
}

// ---------------------------------------------------------------------------
// Exact f64 re-resolution of near-tie rows — compacted-list variant.
// ---------------------------------------------------------------------------
__global__ __launch_bounds__(256) void exact_fix_list(
    const float* __restrict__ q, const float* __restrict__ k,
    u32* __restrict__ idx, const u32* __restrict__ flaglist,
    const u32* __restrict__ count)
{
  __shared__ double qd[D_];
  __shared__ double sd[256];
  __shared__ int sj[256];
  const int tid = threadIdx.x;
  const int cnt = (int)count[0];
  for (int li = blockIdx.x; li < cnt; li += (int)gridDim.x) {
    const int r = (int)flaglist[li];
    const int bh = r >> 11;
    const int i = r & (N_ - 1);
    const float* qr = q + (size_t)r * D_;
    const float* kb = k + (size_t)bh * N_ * D_;
    if (tid < D_) qd[tid] = (double)qr[tid];
    __syncthreads();
    double qsqd = 0.0;
    for (int d = 0; d < D_; ++d) qsqd = fma(qd[d], qd[d], qsqd);
    double bbest = 1e300;
    int bjj = 0;
    for (int j = tid; j <= i; j += 256) {
      const float* kr = kb + (size_t)j * D_;
      double a0 = 0, a1 = 0, s0 = 0, s1 = 0;
      for (int d = 0; d < D_; d += 2) {
        const double k0 = (double)kr[d], k1 = (double)kr[d + 1];
        a0 = fma(qd[d], k0, a0);  a1 = fma(qd[d + 1], k1, a1);
        s0 = fma(k0, k0, s0);     s1 = fma(k1, k1, s1);
      }
      const double raw = (qsqd + (s0 + s1)) - 2.0 * (a0 + a1);
      const double d2 = raw > 0.0 ? raw : 0.0;
      if (d2 < bbest) { bbest = d2; bjj = j; }   // ascending j -> first on tie
    }
    sd[tid] = bbest; sj[tid] = bjj;
    __syncthreads();
    for (int s = 128; s > 0; s >>= 1) {
      if (tid < s) {
        const double ob = sd[tid + s]; const int oj = sj[tid + s];
        if (ob < sd[tid] || (ob == sd[tid] && oj < sj[tid])) {
          sd[tid] = ob; sj[tid] = oj;
        }
      }
      __syncthreads();
    }
    if (tid == 0) idx[r] = (u32)sj[0];
    __syncthreads();
  }
}

// Legacy scan variant (used only if ws is too small for the list).
__global__ __launch_bounds__(256) void exact_fix_scan(
    const float* __restrict__ q, const float* __restrict__ k,
    u32* __restrict__ idx)
{
  __shared__ double qd[D_];
  __shared__ double sd[256];
  __shared__ int sj[256];
  const int tid = threadIdx.x;
  const int rbase = blockIdx.x * (NROWS / 512);
  for (int rr = 0; rr < NROWS / 512; ++rr) {
    const int r = rbase + rr;
    if (!(idx[r] & 0x80000000u)) continue;
    const int bh = r >> 11;
    const int i = r & (N_ - 1);
    const float* qr = q + (size_t)r * D_;
    const float* kb = k + (size_t)bh * N_ * D_;
    if (tid < D_) qd[tid] = (double)qr[tid];
    __syncthreads();
    double qsqd = 0.0;
    for (int d = 0; d < D_; ++d) qsqd = fma(qd[d], qd[d], qsqd);
    double bbest = 1e300;
    int bjj = 0;
    for (int j = tid; j <= i; j += 256) {
      const float* kr = kb + (size_t)j * D_;
      double a0 = 0, a1 = 0, s0 = 0, s1 = 0;
      for (int d = 0; d < D_; d += 2) {
        const double k0 = (double)kr[d], k1 = (double)kr[d + 1];
        a0 = fma(qd[d], k0, a0);  a1 = fma(qd[d + 1], k1, a1);
        s0 = fma(k0, k0, s0);     s1 = fma(k1, k1, s1);
      }
      const double raw = (qsqd + (s0 + s1)) - 2.0 * (a0 + a1);
      const double d2 = raw > 0.0 ? raw : 0.0;
      if (d2 < bbest) { bbest = d2; bjj = j; }
    }
    sd[tid] = bbest; sj[tid] = bjj;
    __syncthreads();
    for (int s = 128; s > 0; s >>= 1) {
      if (tid < s) {
        const double ob = sd[tid + s]; const int oj = sj[tid + s];
        if (ob < sd[tid] || (ob == sd[tid] && oj < sj[tid])) {
          sd[tid] = ob; sj[tid] = oj;
        }
      }
      __syncthreads();
    }
    if (tid == 0) idx[r] = (u32)sj[0];
    __syncthreads();
  }
}

// ---------------------------------------------------------------------------
// Gather: out[r, :] = v[bh, idx[r] & 0xFFFF, :]  (float4-vectorized)
// ---------------------------------------------------------------------------
__global__ __launch_bounds__(256) void gather_v(
    const float* __restrict__ v, const u32* __restrict__ idx,
    float* __restrict__ out)
{
  const int gidx = blockIdx.x * 256 + threadIdx.x;
  const int r = gidx >> 4, c = gidx & 15;
  const u32 j = idx[r] & 0xFFFFu;
  const int bh = r >> 11;
  const float4 val = ((const float4*)(v + ((size_t)bh * N_ + j) * D_))[c];
  ((float4*)(out + (size_t)r * D_))[c] = val;
}

// ---------------------------------------------------------------------------
extern "C" void kernel_launch(void* const* d_in, const int* in_sizes, int n_in,
                              void* d_out, int out_size, void* d_ws,
                              size_t ws_size, hipStream_t stream) {
  const float* q = (const float*)d_in[0];
  const float* k = (const float*)d_in[1];
  const float* v = (const float*)d_in[2];
  float* out = (float*)d_out;

  // Segment scratch in d_out (6 MB of 8 MB; fully overwritten by gather_v).
  // ws: [count 64B | idx 128K | list 128K | ksq 128K | pad | khi 4M | klo 4M]
  u64* bestseg = (u64*)d_out;                                // 4 MB
  u32* secseg = (u32*)(bestseg + (size_t)NROWS * NSEG);      // 2 MB
  u32* count = (u32*)d_ws;
  u32* idx = (u32*)((char*)d_ws + 64);
  u32* flaglist = idx + NROWS;
  float* ksq_g = (float*)((char*)d_ws + 64 + 2 * (size_t)NROWS * 4);
  char* khi_g = (char*)d_ws + 512 * 1024;
  char* klo_g = khi_g + 4 * 1024 * 1024;
  const int use_list = (ws_size >= 64 + 2 * (size_t)NROWS * 4) ? 1 : 0;
  const int pre =
      (ws_size >= 512 * 1024 + 8ull * 1024 * 1024) ? 1 : 0;

  if (pre) {
    prep_split<<<(NROWS * 8) / 256, 256, 0, stream>>>(k, khi_g, klo_g, ksq_g);
    phase1<1><<<NBLK, 256, 0, stream>>>(q, k, khi_g, klo_g, ksq_g,
                                        bestseg, secseg, count);
  } else {
    phase1<0><<<NBLK, 256, 0, stream>>>(q, k, khi_g, klo_g, ksq_g,
                                        bestseg, secseg, count);
  }
  combine_segs<<<NROWS / 256, 256, 0, stream>>>(bestseg, secseg, idx,
                                                flaglist, count, use_list);
  if (use_list)
    exact_fix_list<<<64, 256, 0, stream>>>(q, k, idx, flaglist, count);
  else
    exact_fix_scan<<<512, 256, 0, stream>>>(q, k, idx);
  gather_v<<<(NROWS * (D_ / 4)) / 256, 256, 0, stream>>>(v, idx, out);
}